// Round 20
// baseline (30.335 us; speedup 1.0000x reference)
//
#include <hip/hip_runtime.h>

// MPS batched contraction, SPLIT-CHAIN form. out[b] = e0^T G0 G1 ... G31 e0
// (G_P = xx-weighted pair matrix, rank-1 boundaries) =>
//   u = (G0...G15)^T e0   : left-recurrence, pairs 0..15 ascending (A-chain)
//   v =  G16...G31  e0    : right-recurrence, pairs 31..16 descending (B-chain)
//   out = u . v           : 32-length f32 dot per row
// Serial depth per wave HALVES (16 pair-hops), waves DOUBLE (4096, 4/SIMD).
// R1-R19 falsified LDS BW / chain split / G pipe / x path / prep / TLP /
// vmcnt drain / convoys / icache; the never-varied constant was the 32-hop
// serial chain per wave at 2 waves/SIMD -- this attacks exactly that.
//
// MFMA 32x32x16 f16 (layouts R9/R11/R13-verified):
//   A-op row = lane&31, k = 8*(lane>>5)+e; C/D col = lane&31 (batch row),
//   row i = (reg&3)+8*(reg>>2)+4*(lane>>5).
// A-chain frags (Gf): row=d, k encodes (pq,l): kf=pq*2+lh,
//   l = 16*lh + (e&3)+8*(e>>2)+4*h  => U_kf[e] = f16(acc[e+8*lh])*xx[pq].
// B-chain frags (Gf2, l<->d mirrored): row=l, k encodes (pq,d): kf=pq*2+dh,
//   d = 16*dh + (e&3)+8*(e>>2)+4*h  => U_kf[e] = f16(acc[e+8*dh])*xx[pq].
// Same-lane property holds identically -> main-loop code is shared.

typedef _Float16 half8 __attribute__((ext_vector_type(8)));
typedef _Float16 half4 __attribute__((ext_vector_type(4)));
typedef float floatx16 __attribute__((ext_vector_type(16)));
typedef float f32x4 __attribute__((ext_vector_type(4)));

#define NPAIRS 32
#define GSTEP 8192      // halfs per step chunk: 4096 (A stream) + 4096 (B stream)
#define XSTRIDE 129     // padded half4 units per quad line (bank spread)
#define GF2_OFS 131072  // halfs: Gf2 starts 256 KB into d_ws

// ---------------- prep: one block per (pair, pq); packs Gf AND Gf2 --------
__global__ void mps_prep_pair(const float* __restrict__ A, _Float16* __restrict__ Gf) {
    __shared__ float sA[1024];   // [l][m]
    __shared__ float sB[1024];   // [m][d]
    __shared__ float sG[1024];   // [l][d]
    const int blk = blockIdx.x;          // 0..127 = P*4 + pq
    const int P   = blk >> 2;
    const int pq  = blk & 3;
    const int p   = pq >> 1, q = pq & 1;
    const int tid = threadIdx.x;         // 0..255
    const int row = tid >> 3;            // 0..31
    const int c4  = (tid & 7) * 4;       // 0,4,...,28

    *(f32x4*)&sA[row * 32 + c4] =
        *(const f32x4*)(A + ((size_t)(2 * P) * 32 + row) * 64 + p * 32 + c4);
    *(f32x4*)&sB[row * 32 + c4] =
        *(const f32x4*)(A + ((size_t)(2 * P + 1) * 32 + row) * 64 + q * 32 + c4);
    __syncthreads();
    {
        f32x4 acc;
        acc[0] = 0.f; acc[1] = 0.f; acc[2] = 0.f; acc[3] = 0.f;
        for (int m = 0; m < 32; ++m) {
            const float av = sA[row * 32 + m];
            const f32x4 bv = *(const f32x4*)&sB[m * 32 + c4];
            acc[0] += av * bv[0]; acc[1] += av * bv[1];
            acc[2] += av * bv[2]; acc[3] += av * bv[3];
        }
        *(f32x4*)&sG[row * 32 + c4] = acc;
    }
    __syncthreads();
    const int lane = tid & 63;
    const int h    = lane >> 5;
    if (tid < 128) {                     // Gf (A-chain), pair-slot P
        const int lh = tid >> 6;
        const int d  = lane & 31;
        half8 v;
#pragma unroll
        for (int e = 0; e < 8; ++e) {
            const int l = 16 * lh + (e & 3) + 8 * (e >> 2) + 4 * h;
            v[e] = (_Float16)sG[l * 32 + d];
        }
        reinterpret_cast<half8*>(Gf)[((size_t)P * 8 + pq * 2 + lh) * 64 + lane] = v;
    } else {                             // Gf2 (B-chain), REVERSED pair-slot 31-P
        const int dh = (tid >> 6) & 1;
        const int l  = lane & 31;
        const int j  = 31 - P;
        half8 v;
#pragma unroll
        for (int e = 0; e < 8; ++e) {
            const int d = 16 * dh + (e & 3) + 8 * (e >> 2) + 4 * h;
            v[e] = (_Float16)sG[l * 32 + d];
        }
        reinterpret_cast<half8*>(Gf + GF2_OFS)[((size_t)j * 8 + pq * 2 + dh) * 64 + lane] = v;
    }
}

// ---------------- main kernel ----------------
#define MF32(A_, B_, C_) __builtin_amdgcn_mfma_f32_32x32x16_f16(A_, B_, C_, 0, 0, 0)

__global__ __launch_bounds__(512, 2) void mps_main(const float* __restrict__ x,
                                                   const _Float16* __restrict__ Gf,
                                                   float* __restrict__ out) {
    __shared__ __align__(16) _Float16 smG[2 * GSTEP];     // 32 KB (dbuf)
    __shared__ __align__(8)  half4    smX[32 * XSTRIDE];  // 33 KB, [quad][row]

    const int tid  = threadIdx.x;                // 0..511
    const int lane = tid & 63;
    const int wid  = tid >> 6;                   // 0..7
    const int w4   = wid & 3;
    const int is_b = wid >> 2;                   // 0 = u-chain, 1 = v-chain
    const int brow = blockIdx.x * 128;
    const int col  = lane & 31;
    const int h    = lane >> 5;
    const int r    = w4 * 32 + col;              // row within block (0..127)

    const _Float16* GfB = Gf + GF2_OFS;

    // stage step 0: wave wid stages rec wid of stream A and rec wid of stream B
    {
        const _Float16* gA = Gf + wid * 512 + lane * 8;
        __builtin_amdgcn_global_load_lds(
            (const __attribute__((address_space(1))) void*)gA,
            (__attribute__((address_space(3))) void*)&smG[wid * 512], 16, 0, 0);
        const _Float16* gB = GfB + wid * 512 + lane * 8;
        __builtin_amdgcn_global_load_lds(
            (const __attribute__((address_space(1))) void*)gB,
            (__attribute__((address_space(3))) void*)&smG[4096 + wid * 512], 16, 0, 0);
    }

    // x -> LDS f16 transposed [quad][row]: coalesced f32x4 global reads
#pragma unroll
    for (int i = 0; i < 8; ++i) {
        const int j   = i * 512 + tid;           // 0..4095
        const int row = j >> 5, q = j & 31;
        const f32x4 v = *(const f32x4*)(x + (size_t)(brow + row) * 128 + 4 * q);
        half4 hv;
        hv[0] = (_Float16)v[0]; hv[1] = (_Float16)v[1];
        hv[2] = (_Float16)v[2]; hv[3] = (_Float16)v[3];
        smX[q * XSTRIDE + row] = hv;
    }

    floatx16 zv;
#pragma unroll
    for (int i = 0; i < 16; ++i) zv[i] = 0.f;

    // acc: u-chain = left[l] layout; v-chain = v[d] layout. Both init e0:
    // index 0 -> reg 0, h=0 (lanes 0..31).
    floatx16 acc;
#pragma unroll
    for (int i = 0; i < 16; ++i) acc[i] = 0.f;
    if (lane < 32) acc[0] = 1.f;

    __syncthreads();                              // x + step 0 resident

    // 16 steps; each wave applies ONE pair per step (A: pair s; B: pair 31-s).
#pragma unroll 1
    for (int s = 0; s < 16; ++s) {
        const int buf = s & 1;
        if (s < 15) {
            const int nbuf = buf ^ 1;
            const _Float16* gA = Gf + (size_t)(s + 1) * 4096 + wid * 512 + lane * 8;
            __builtin_amdgcn_global_load_lds(
                (const __attribute__((address_space(1))) void*)gA,
                (__attribute__((address_space(3))) void*)&smG[nbuf * GSTEP + wid * 512],
                16, 0, 0);
            const _Float16* gB = GfB + (size_t)(s + 1) * 4096 + wid * 512 + lane * 8;
            __builtin_amdgcn_global_load_lds(
                (const __attribute__((address_space(1))) void*)gB,
                (__attribute__((address_space(3))) void*)&smG[nbuf * GSTEP + 4096 + wid * 512],
                16, 0, 0);
        }
        {
            const int qidx = is_b ? (31 - s) : s;
            const half4 xq = smX[qidx * XSTRIDE + r];
            const _Float16 w00 = xq[0] * xq[2];
            const _Float16 w01 = xq[0] * xq[3];
            const _Float16 w10 = xq[1] * xq[2];
            const _Float16 w11 = xq[1] * xq[3];
            const _Float16* gb = &smG[buf * GSTEP + is_b * 4096 + lane * 8];
            const half8 G0 = *(const half8*)(gb + 0 * 512);
            const half8 G1 = *(const half8*)(gb + 1 * 512);
            const half8 G2 = *(const half8*)(gb + 2 * 512);
            const half8 G3 = *(const half8*)(gb + 3 * 512);
            const half8 G4 = *(const half8*)(gb + 4 * 512);
            const half8 G5 = *(const half8*)(gb + 5 * 512);
            const half8 G6 = *(const half8*)(gb + 6 * 512);
            const half8 G7 = *(const half8*)(gb + 7 * 512);
            half8 FA0, FA1;
#pragma unroll
            for (int i_ = 0; i_ < 8; ++i_) {
                FA0[i_] = (_Float16)acc[i_];
                FA1[i_] = (_Float16)acc[8 + i_];
            }
            floatx16 t;
            t = MF32(G0, FA0 * w00, zv);
            t = MF32(G1, FA1 * w00, t);
            t = MF32(G2, FA0 * w01, t);
            t = MF32(G3, FA1 * w01, t);
            t = MF32(G4, FA0 * w10, t);
            t = MF32(G5, FA1 * w10, t);
            t = MF32(G6, FA0 * w11, t);
            t = MF32(G7, FA1 * w11, t);
            acc = t;
        }
        __syncthreads();
    }

    // Combine: write u,v transposed [idx][row] into smG (f32), dot per row.
    {
        float* uvb = (float*)smG;                 // [2][32][128] f32 = 32 KB
        const int vofs = is_b * 4096;
#pragma unroll
        for (int reg = 0; reg < 16; ++reg) {
            const int li = (reg & 3) + 8 * (reg >> 2) + 4 * h;
            uvb[vofs + li * 128 + r] = acc[reg];  // consecutive r -> conflict-free
        }
        __syncthreads();
        if (tid < 128) {
            float sum = 0.f;
#pragma unroll
            for (int li = 0; li < 32; ++li)
                sum += uvb[li * 128 + tid] * uvb[4096 + li * 128 + tid];
            out[brow + tid] = sum;
        }
    }
}

extern "C" void kernel_launch(void* const* d_in, const int* in_sizes, int n_in,
                              void* d_out, int out_size, void* d_ws, size_t ws_size,
                              hipStream_t stream) {
    const float* x = (const float*)d_in[0];   // [65536][64][2] f32
    const float* A = (const float*)d_in[1];   // [64][32][2][32] f32
    float* outp = (float*)d_out;              // [65536] f32
    _Float16* Gf = (_Float16*)d_ws;           // 512 KB: Gf (256K) + Gf2 (256K)

    hipLaunchKernelGGL(mps_prep_pair, dim3(NPAIRS * 4), dim3(256), 0, stream, A, Gf);
    hipLaunchKernelGGL(mps_main, dim3(65536 / 128), dim3(512), 0, stream, x, Gf, outp);
}